// Round 10
// baseline (271.042 us; speedup 1.0000x reference)
//
#include <hip/hip_runtime.h>
#include <math.h>

#define NPATH 23
#define NEDGE 50000
#define NCHAN 32
#define NWROW 736      // 23*32 weight row length
#define OUTW  99       // concatenated output width
#define TTOT  439      // total T slots = sum n1*n3
#define EPB   2        // edges per block
#define NTHR  256

// Path tables (derived from the reference's _build_paths; verified rounds 0-9)
constexpr int L1[NPATH]    = {0,0,0,0,1,1,1,1,1,1,2,2,2,2,2,2,2,3,3,3,3,3,3};
constexpr int L2[NPATH]    = {0,1,2,3,0,1,1,2,2,3,0,1,1,2,2,3,3,0,1,2,2,3,3};
constexpr int L3[NPATH]    = {0,1,2,3,1,0,2,1,3,2,2,1,3,0,2,1,3,3,2,1,3,0,2};
constexpr int POS[NPATH]   = {0,4,10,17,5,1,11,6,18,12,13,7,19,2,14,8,20,21,15,9,22,3,16};
constexpr int OOFF[NPATH]  = {0,4,7,12,19,1,34,22,39,46,51,31,61,2,73,25,78,85,68,28,92,3,56};
constexpr int TOFF[NPATH]  = {0,1,4,9,16,25,28,43,52,73,88,113,128,163,168,193,208,243,292,327,348,397,404};
constexpr int LOFF[4]      = {0,1,4,9};

// 4-way path split, one group per WAVE. Constraints: FMA balance
// (113/108/116/102) AND k-rows (sum n3) <= 32 per group (23/26/22/28) so
// 2*E <= 64 lanes can each own one padded T k-row in phase B.
constexpr unsigned GMASKS[4] = {0x122028u, 0x211405u, 0x444100u, 0x88AD2u};

constexpr int PAD(int n1){ return n1 <= 3 ? 4 : 8; }

// padded T layout offsets: [path][k][i_pad]
struct PT { int v[NPATH]; int total; };
constexpr PT make_ptoff(){
    PT t{}; int a = 0;
    for(int p = 0; p < NPATH; ++p){ t.v[p] = a; a += (2*L3[p]+1)*PAD(2*L1[p]+1); }
    t.total = a;
    return t;
}
constexpr PT PTOF = make_ptoff();
static_assert(PTOF.total == 632, "padded T size");
#define TSZ 632

// phase-B entry table: one entry per (path,k) k-row, per group.
// bits: 0-8 slot0(=TOFF+k), 9-11 n3, 12-14 n1, 15 pad8, 16-25 dst, 26-27 q0
struct BTab { unsigned v[4][28]; int cnt[4]; };
constexpr BTab make_btab(){
    BTab b{};
    for(int g = 0; g < 4; ++g){
        int n = 0;
        for(int p = 0; p < NPATH; ++p){
            if(!((GMASKS[g] >> p) & 1u)) continue;
            int n1 = 2*L1[p]+1, n3 = 2*L3[p]+1;
            int o2 = LOFF[L2[p]];
            int q0 = o2 >> 2;                    // quad window start (2 quads)
            for(int k = 0; k < n3; ++k){
                b.v[g][n++] = (unsigned)(TOFF[p]+k)
                            | ((unsigned)n3 << 9) | ((unsigned)n1 << 12)
                            | ((unsigned)(PAD(n1)==8 ? 1 : 0) << 15)
                            | ((unsigned)(PTOF.v[p] + k*PAD(n1)) << 16)
                            | ((unsigned)q0 << 26);
            }
        }
        b.cnt[g] = n;
    }
    return b;
}
constexpr BTab BT = make_btab();

typedef _Float16 __attribute__((ext_vector_type(4))) h4;

__device__ __forceinline__ int imx(int a, int b){ return a > b ? a : b; }
__device__ __forceinline__ int imn(int a, int b){ return a < b ? a : b; }

__device__ __forceinline__ double factd(int n){
    double r = 1.0;
    for(int i = 2; i <= n; ++i) r *= (double)i;
    return r;
}

// ---------------------------------------------------------------------------
// Setup: reference-exact _wigner_3j (verified R0/R6), emitting the DENSE
// [439 slots][16 jfull] fp32 matrix cgd2 (zeros outside each l2 block).
// ---------------------------------------------------------------------------
__global__ __launch_bounds__(512) void cg_setup(float* __restrict__ cgd2){
    const int p  = blockIdx.x;
    const int j1 = L1[p], j2 = L2[p], j3 = L3[p];
    const int n1 = 2*j1+1, n2 = 2*j2+1, n3 = 2*j3+1;
    const int o2 = LOFF[j2];
    const int ntot = n1*n2*n3;
    const int t = threadIdx.x;

    __shared__ double scg[343];
    __shared__ double qre[3][49];
    __shared__ double qim[3][49];
    __shared__ double red[512];

    if(t < ntot){
        int a   = t / (n2*n3);
        int rem = t - a*(n2*n3);
        int b   = rem / n3;
        int g   = rem - b*n3;
        int m1 = a - j1, m2 = b - j2, m3 = g - j3;
        double val = 0.0;
        if(m1 + m2 == m3){
            int vmin = imx(imx(-j1 + j2 + m3, -j1 + m1), 0);
            int vmax = imn(imn(j2 + j3 + m1, j3 - j1 + j2), j3 + m3);
            double C = sqrt((2.0*j3 + 1.0) * factd(j3 + j1 - j2) * factd(j3 - j1 + j2)
                            * factd(j1 + j2 - j3) / factd(j1 + j2 + j3 + 1));
            C *= sqrt(factd(j3 + m3) * factd(j3 - m3) * factd(j1 - m1)
                      * factd(j1 + m1) * factd(j2 - m2) * factd(j2 + m2));
            double S = 0.0;
            for(int v = vmin; v <= vmax; ++v){
                double sgn = ((v + j2 + m2) & 1) ? -1.0 : 1.0;
                S += sgn * factd(j2 + j3 + m1 - v) * factd(j1 - m1 + v)
                     / (factd(v) * factd(j3 - j1 + j2 - v) * factd(j3 + m3 - v)
                        * factd(v + j1 - j2 - m3));
            }
            val = C * S;
        }
        scg[t] = val;
    }

    if(t < 3){
        int l = (t == 0) ? j1 : ((t == 1) ? j2 : j3);
        int n = 2*l + 1;
        double* QR = qre[t];
        double* QI = qim[t];
        for(int i = 0; i < 49; ++i){ QR[i] = 0.0; QI[i] = 0.0; }
        const double is2 = 0.70710678118654752440;
        for(int m = -l; m < 0; ++m){
            QR[(l+m)*n + (l-m)] = is2;
            QI[(l+m)*n + (l+m)] = -is2;
        }
        QR[l*n + l] = 1.0;
        for(int m = 1; m <= l; ++m){
            double s = (m & 1) ? -1.0 : 1.0;
            QR[(l+m)*n + (l+m)] = s * is2;
            QI[(l+m)*n + (l-m)] = s * is2;
        }
        double fr, fi;
        switch(l & 3){
            case 0: fr = 1.0;  fi = 0.0;  break;
            case 1: fr = 0.0;  fi = -1.0; break;
            case 2: fr = -1.0; fi = 0.0;  break;
            default: fr = 0.0; fi = 1.0;  break;
        }
        for(int i = 0; i < n*n; ++i){
            double re = QR[i], im = QI[i];
            QR[i] = re*fr - im*fi;
            QI[i] = re*fi + im*fr;
        }
    }
    __syncthreads();

    double val = 0.0;
    if(t < ntot){
        int j   = t / (n2*n3);
        int rem = t - j*(n2*n3);
        int lq  = rem / n3;
        int m   = rem - lq*n3;
        double acc = 0.0;
        for(int i = 0; i < n1; ++i){
            double q1r = qre[0][i*n1 + j], q1i = qim[0][i*n1 + j];
            if(q1r == 0.0 && q1i == 0.0) continue;
            for(int k = 0; k < n2; ++k){
                double q2r = qre[1][k*n2 + lq], q2i = qim[1][k*n2 + lq];
                if(q2r == 0.0 && q2i == 0.0) continue;
                double ar = q1r*q2r - q1i*q2i;
                double ai = q1r*q2i + q1i*q2r;
                for(int n = 0; n < n3; ++n){
                    double cv = scg[(i*n2 + k)*n3 + n];
                    if(cv == 0.0) continue;
                    double q3r = qre[2][n*n3 + m];
                    double q3i = -qim[2][n*n3 + m];
                    acc += cv * (ar*q3r - ai*q3i);
                }
            }
        }
        val = acc;
    }

    red[t] = val * val;
    __syncthreads();
    if(t < 343) scg[t] = val;
    for(int s2 = 256; s2 > 0; s2 >>= 1){
        if(t < s2) red[t] += red[t + s2];
        __syncthreads();
    }
    const double scale = sqrt(2.0*j3 + 1.0) / sqrt(red[0]);

    for(int u = t; u < n1*n3*16; u += 512){
        int sl = u >> 4, jf = u & 15;
        int i  = sl / n3, k = sl - i*n3;
        int j  = jf - o2;
        double v2 = (j >= 0 && j < n2) ? scg[(i*n2 + j)*n3 + k] : 0.0;
        cgd2[(size_t)(TOFF[p] + sl)*16 + jf] = (float)(v2 * scale);
    }
}

// ---------------------------------------------------------------------------
// w prefetch, templated on group -> compile-time offsets.
// ---------------------------------------------------------------------------
template<int G>
__device__ __forceinline__ void prefetchW(const float* __restrict__ wbase,
                                          float* __restrict__ wreg)
{
    constexpr unsigned mask = GMASKS[G];
    #pragma unroll
    for(int p = 0; p < NPATH; ++p){
        if((mask >> p) & 1u)
            wreg[__builtin_popcount(mask & ((1u << p) - 1u))] = wbase[POS[p]*NCHAN];
    }
}

// ---------------------------------------------------------------------------
// Phase B: each lane owns one padded T k-row of its wave's group (both edges).
// Reads y + cgd2 quad-windows from global (L1-hot), writes 1-2 ds_write_b128.
// ---------------------------------------------------------------------------
template<int G>
__device__ __forceinline__ void phaseB(int lane, int e0,
                                       const float* __restrict__ y,
                                       const float* __restrict__ cgd2,
                                       float* __restrict__ TsL)
{
    constexpr int E = BT.cnt[G];
    if(lane < 2*E){
        const int el  = (lane >= E) ? 1 : 0;
        const int idx = lane - el*E;
        const unsigned ent = BT.v[G][idx];
        const int slot0 = ent & 511;
        const int n3    = (ent >> 9)  & 7;
        const int n1    = (ent >> 12) & 7;
        const int pad8  = (ent >> 15) & 1;
        const int dst   = (ent >> 16) & 1023;
        const int q0    = (ent >> 26) & 3;

        const float* yq = y + (size_t)(e0 + el)*16 + q0*4;
        float4 y0 = *(const float4*)yq;
        float4 y1 = *(const float4*)(yq + 4);   // q0<=2, window in-bounds

        float T[8];
        #pragma unroll
        for(int i = 0; i < 8; ++i) T[i] = 0.f;
        #pragma unroll
        for(int i = 0; i < 7; ++i){
            if(i < n1){
                const float* cr = cgd2 + (size_t)(slot0 + i*n3)*16 + q0*4;
                float4 c0 = *(const float4*)cr;
                float4 c1 = *(const float4*)(cr + 4);
                float a;
                a = fmaf(c0.x, y0.x, 0.f);  a = fmaf(c0.y, y0.y, a);
                a = fmaf(c0.z, y0.z, a);    a = fmaf(c0.w, y0.w, a);
                a = fmaf(c1.x, y1.x, a);    a = fmaf(c1.y, y1.y, a);
                a = fmaf(c1.z, y1.z, a);    a = fmaf(c1.w, y1.w, a);
                T[i] = a;
            }
        }
        float* d = TsL + el*TSZ + dst;
        *(float4*)d = float4{T[0], T[1], T[2], T[3]};
        if(pad8) *((float4*)d + 1) = float4{T[4], T[5], T[6], T[7]};
    }
}

// ---------------------------------------------------------------------------
// Phase C: compile-time mask, k-major b128 T reads, fp16 pair-packed writes.
// ---------------------------------------------------------------------------
template<int G>
__device__ __forceinline__ void phaseC(const float* __restrict__ xr,
                                       const float* __restrict__ wreg,
                                       const float* __restrict__ Te,
                                       _Float16* __restrict__ ob)
{
    constexpr unsigned mask = GMASKS[G];
    #pragma unroll
    for(int p = 0; p < NPATH; ++p){
        if(!((mask >> p) & 1u)) continue;          // folds after unroll
        const int widx = __builtin_popcount(mask & ((1u << p) - 1u));
        const int n1  = 2*L1[p] + 1;
        const int n3  = 2*L3[p] + 1;
        const int o1  = LOFF[L1[p]];
        const int pad = PAD(n1);
        const float wp = wreg[widx];

        float acc[7];
        #pragma unroll
        for(int k = 0; k < n3; ++k){
            const float* tr = Te + PTOF.v[p] + k*pad;
            float4 t0 = *(const float4*)tr;
            float a = xr[o1] * t0.x;
            if(n1 > 1){
                a = fmaf(xr[o1+1], t0.y, a);
                a = fmaf(xr[o1+2], t0.z, a);
            }
            if(n1 > 3){
                a = fmaf(xr[o1+3], t0.w, a);
                float4 t1 = *((const float4*)tr + 1);
                a = fmaf(xr[o1+4], t1.x, a);
                if(n1 > 5){
                    a = fmaf(xr[o1+5], t1.y, a);
                    a = fmaf(xr[o1+6], t1.z, a);
                }
            }
            acc[k] = a * wp;
        }

        // pack-store: optional lead half, b32 pairs, optional tail half
        const int off  = OOFF[p];
        const int lead = off & 1;
        if(lead) ob[off] = (_Float16)acc[0];
        const int npair = (n3 - lead) >> 1;
        #pragma unroll
        for(int kk = 0; kk < npair; ++kk){
            const int k0 = lead + 2*kk;
            _Float16 h0 = (_Float16)acc[k0];
            _Float16 h1 = (_Float16)acc[k0+1];
            unsigned u = (unsigned)__builtin_bit_cast(unsigned short, h0)
                       | ((unsigned)__builtin_bit_cast(unsigned short, h1) << 16);
            *reinterpret_cast<unsigned*>(
                reinterpret_cast<char*>(ob) + (size_t)(off + k0)*2) = u;
        }
        if((n3 - lead) & 1) ob[off + n3 - 1] = (_Float16)acc[n3-1];
    }
}

// ---------------------------------------------------------------------------
// Main kernel: 2 edges/block, 256 threads (4 waves), wave = path group,
// lane = (el, c). Each wave builds exactly the T rows it consumes ->
// wave-local lgkmcnt sync instead of a block barrier. Single __syncthreads
// before the coalesced flush. obuf rows padded to 100 halfs (4B-aligned).
// ---------------------------------------------------------------------------
__global__ __launch_bounds__(NTHR, 6) void tp_main(
    const float* __restrict__ x, const float* __restrict__ y,
    const float* __restrict__ w, const float* __restrict__ cgd2,
    float* __restrict__ out)
{
    __shared__ __align__(16) _Float16 obuf[EPB*NCHAN*100];  // 6400 h, 12.8 KB
    __shared__ __align__(16) float Ts[EPB*TSZ];             // 1264 f, 5.06 KB

    const int tid = threadIdx.x;
    const int e0  = blockIdx.x * EPB;

    const int lane = tid & 63;
    const int c    = tid & 31;          // channel
    const int el   = (tid >> 5) & 1;    // edge within block
    const int grp  = tid >> 6;          // wave id = path group (0..3)
    const int e    = e0 + el;

    // prefetch x (4x float4) — consumed after the wave-local sync
    const float4* xp = reinterpret_cast<const float4*>(x + (size_t)(e*NCHAN + c)*16);
    float4 x0 = xp[0], x1 = xp[1], x2 = xp[2], x3 = xp[3];

    // prefetch THIS group's w values with compile-time offsets
    const float* wbase = w + (size_t)e*NWROW + c;
    float wreg[10];
    switch(grp){
        case 0: prefetchW<0>(wbase, wreg); break;
        case 1: prefetchW<1>(wbase, wreg); break;
        case 2: prefetchW<2>(wbase, wreg); break;
        default: prefetchW<3>(wbase, wreg); break;
    }

    // Phase B: this wave's T k-rows (both edges), straight into LDS
    switch(grp){
        case 0: phaseB<0>(lane, e0, y, cgd2, Ts); break;
        case 1: phaseB<1>(lane, e0, y, cgd2, Ts); break;
        case 2: phaseB<2>(lane, e0, y, cgd2, Ts); break;
        default: phaseB<3>(lane, e0, y, cgd2, Ts); break;
    }

    // wave-local: writes by this wave's lanes -> visible to this wave's reads
    asm volatile("s_waitcnt lgkmcnt(0)" ::: "memory");
    __builtin_amdgcn_sched_barrier(0);

    // Phase C
    float xr[16];
    xr[0]=x0.x;  xr[1]=x0.y;  xr[2]=x0.z;  xr[3]=x0.w;
    xr[4]=x1.x;  xr[5]=x1.y;  xr[6]=x1.z;  xr[7]=x1.w;
    xr[8]=x2.x;  xr[9]=x2.y;  xr[10]=x2.z; xr[11]=x2.w;
    xr[12]=x3.x; xr[13]=x3.y; xr[14]=x3.z; xr[15]=x3.w;

    const float* Te = Ts + el*TSZ;
    _Float16* ob = obuf + (el*NCHAN + c)*100;

    switch(grp){
        case 0: phaseC<0>(xr, wreg, Te, ob); break;
        case 1: phaseC<1>(xr, wreg, Te, ob); break;
        case 2: phaseC<2>(xr, wreg, Te, ob); break;
        default: phaseC<3>(xr, wreg, Te, ob); break;
    }
    __syncthreads();

    // Flush: 1600 h4 chunks; skip the per-row pad half (col 99)
    const h4* ob4 = reinterpret_cast<const h4*>(obuf);
    for(int idx = tid; idx < EPB*NCHAN*25; idx += NTHR){
        int row = idx / 25;             // el*32 + c
        int j   = idx - row*25;
        h4 hv = ob4[idx];
        float* base = out + (size_t)(e0 + (row >> 5))*(NCHAN*OUTW)
                          + (size_t)(row & 31)*OUTW + j*4;
        base[0] = (float)hv[0];
        base[1] = (float)hv[1];
        base[2] = (float)hv[2];
        if(j < 24) base[3] = (float)hv[3];
    }
}

extern "C" void kernel_launch(void* const* d_in, const int* in_sizes, int n_in,
                              void* d_out, int out_size, void* d_ws, size_t ws_size,
                              hipStream_t stream)
{
    const float* x  = (const float*)d_in[0];
    const float* y  = (const float*)d_in[1];
    const float* wt = (const float*)d_in[2];
    float* out = (float*)d_out;
    float* cgd2 = (float*)d_ws;   // 439*16 floats = 28.1 KB of scratch

    cg_setup<<<NPATH, 512, 0, stream>>>(cgd2);
    tp_main<<<NEDGE/EPB, NTHR, 0, stream>>>(x, y, wt, cgd2, out);
}